// Round 10
// baseline (252.467 us; speedup 1.0000x reference)
//
#include <hip/hip_runtime.h>
#include <math.h>

#define B_   128
#define T_   50
#define MI_  32
#define E_   128
#define EW_  16
#define D_   144
#define G_   432        // 3*D
#define N_   (B_*T_)    // 6400

typedef short bf16x8 __attribute__((ext_vector_type(8)));   // 8 bf16 = 4 VGPR
typedef float f32x4  __attribute__((ext_vector_type(4)));

__device__ __forceinline__ short f2bf(float f) {            // RNE fp32->bf16
    unsigned u = __float_as_uint(f);
    u = (u + 0x7FFFu + ((u >> 16) & 1u)) >> 16;
    return (short)u;
}
__device__ __forceinline__ float bf2f(short s) {
    return __uint_as_float(((unsigned)(unsigned short)s) << 16);
}

// ---------------------------------------------------------------------------
// K1: basket embedding v2 — parallel gather (R7, kept).
// ---------------------------------------------------------------------------
__global__ __launch_bounds__(256) void embed_kernel(
    const int* __restrict__ x,            // [N_][33]
    const float* __restrict__ encode_w,   // [100000][128]  (row 0 == 0)
    const float* __restrict__ wchange_w,  // [2][16]
    float* __restrict__ seq)              // [N_][144]
{
    int n = blockIdx.x;
    int tid = threadIdx.x;
    int i = tid >> 3;        // item 0..31
    int j = tid & 7;         // col chunk [16j, 16j+16)

    __shared__ int xi[33];
    __shared__ __align__(16) float part[32 * 132];
    __shared__ float cntf[32];

    if (tid < 33) xi[tid] = x[n * 33 + tid];
    __syncthreads();

    int it = xi[i];
    const float* row = &encode_w[(size_t)it * E_];
    float4 v0 = *(const float4*)&row[16 * j + 0];
    float4 v1 = *(const float4*)&row[16 * j + 4];
    float4 v2 = *(const float4*)&row[16 * j + 8];
    float4 v3 = *(const float4*)&row[16 * j + 12];

    float* p = &part[i * 132 + 16 * j];
    *(float4*)&p[0]  = v0;
    *(float4*)&p[4]  = v1;
    *(float4*)&p[8]  = v2;
    *(float4*)&p[12] = v3;
    if (j == 0) cntf[i] = (it != 0) ? 1.f : 0.f;
    __syncthreads();

    if (tid < E_) {
        int c = tid;
        float s = 0.f, cn = 0.f;
        #pragma unroll
        for (int k = 0; k < 32; ++k) {
            s  += part[k * 132 + c];
            cn += cntf[k];
        }
        seq[n * D_ + c] = s / fmaxf(cn, 1.f);
    } else if (tid < E_ + EW_) {
        int c = tid - E_;
        seq[n * D_ + E_ + c] = wchange_w[xi[32] * EW_ + c];
    }
}

// ---------------------------------------------------------------------------
// K2/K4: C[M][N] = A[M][144] * Bw[N][144]^T + bias[N].  (unchanged)
// ---------------------------------------------------------------------------
#define GK   144
#define GBK  48
#define GPAD 68

__global__ __launch_bounds__(256) void gemm_bias_kernel(
    const float* __restrict__ A,
    const float* __restrict__ Bw,
    const float* __restrict__ bias,
    float* __restrict__ C,
    int M, int N)
{
    __shared__ float As[GBK * GPAD];
    __shared__ float Bs[GBK * GPAD];

    int tid = threadIdx.x;
    int row0 = blockIdx.x * 64;
    int col0 = blockIdx.y * 64;
    int tx = tid & 15;
    int ty = tid >> 4;

    float acc[4][4] = {};

    int sr = tid >> 2;
    int skq0 = tid & 3;

    for (int k0 = 0; k0 < GK; k0 += GBK) {
        __syncthreads();
        #pragma unroll
        for (int i = 0; i < 3; ++i) {
            int kq = skq0 + i * 4;
            float4 a = *(const float4*)&A[(size_t)(row0 + sr) * GK + k0 + kq * 4];
            int nrow = col0 + sr;
            float4 b = make_float4(0.f, 0.f, 0.f, 0.f);
            if (nrow < N)
                b = *(const float4*)&Bw[(size_t)nrow * GK + k0 + kq * 4];
            As[(kq * 4 + 0) * GPAD + sr] = a.x;
            As[(kq * 4 + 1) * GPAD + sr] = a.y;
            As[(kq * 4 + 2) * GPAD + sr] = a.z;
            As[(kq * 4 + 3) * GPAD + sr] = a.w;
            Bs[(kq * 4 + 0) * GPAD + sr] = b.x;
            Bs[(kq * 4 + 1) * GPAD + sr] = b.y;
            Bs[(kq * 4 + 2) * GPAD + sr] = b.z;
            Bs[(kq * 4 + 3) * GPAD + sr] = b.w;
        }
        __syncthreads();

        #pragma unroll 4
        for (int k = 0; k < GBK; ++k) {
            float4 a4 = *(const float4*)&As[k * GPAD + ty * 4];
            float4 b4 = *(const float4*)&Bs[k * GPAD + tx * 4];
            float av[4] = {a4.x, a4.y, a4.z, a4.w};
            float bv[4] = {b4.x, b4.y, b4.z, b4.w};
            #pragma unroll
            for (int i = 0; i < 4; ++i)
                #pragma unroll
                for (int j = 0; j < 4; ++j)
                    acc[i][j] = fmaf(av[i], bv[j], acc[i][j]);
        }
    }

    int c = col0 + tx * 4;
    if (c < N) {
        float4 bb = *(const float4*)&bias[c];
        #pragma unroll
        for (int i = 0; i < 4; ++i) {
            int r = row0 + ty * 4 + i;
            float4 o;
            o.x = acc[i][0] + bb.x;
            o.y = acc[i][1] + bb.y;
            o.z = acc[i][2] + bb.z;
            o.w = acc[i][3] + bb.w;
            *(float4*)&C[(size_t)r * N + c] = o;
        }
    }
}

// ---------------------------------------------------------------------------
// K3: GRU v8 — MFMA.  7 VALU variants all hit a ~2600cy/step structural floor
// (MfmaUtil=0 on matmul-shaped work).  New: 8 blocks x 512 thr; block owns 16
// batches.  Per step gh[16][432] = h[16][144] @ w_hh^T via
// mfma_f32_16x16x32_bf16: 27 n-tiles x 5 k-iters (K padded 160).  W frags
// register-resident (<=4 tiles/wave x 5 kt x 4 VGPR = 80), loaded once.
// Precision: h split hi+lo bf16 (2 MFMA passes; W single bf16) -> only
// W-quant residual (~4e-4 final) vs 2.7e-3 threshold.  h_old kept in thread
// registers; gate fused over all 512 threads; hseq writes deferred past the
// barrier.  Layouts (m89/m120-verified): A[m=lane&15][k=quad*8+j];
// B[n=lane&15][k=quad*8+j]; C col=lane&15=n, row=quad*4+reg=m.
// LDS: hH/hL bf16 [16][168] (stride 168 -> 2-way banks, free);
// gh fp32 stride 434 (434%8==2 -> writes exactly 2-way, reads 2-way: free).
// ---------------------------------------------------------------------------
__global__ __launch_bounds__(512, 1) void gru_kernel(
    const float* __restrict__ gi,     // [N_][432]
    const float* __restrict__ w_hh,   // [432][144]
    const float* __restrict__ b_hh,   // [432]
    const float* __restrict__ h0,     // [128][144]
    float* __restrict__ hseq,         // [N_][144]
    float* __restrict__ hlast)        // [128][144]
{
    int bb   = blockIdx.x;            // batch group (16 batches)
    int tid  = threadIdx.x;
    int wave = tid >> 6;              // 0..7
    int lane = tid & 63;
    int ln   = lane & 15;
    int qd   = lane >> 4;

    __shared__ short hH[16 * 168];    // h hi, bf16, k-padded to 160 (zeros)
    __shared__ short hL[16 * 168];    // h lo
    __shared__ float gh[16 * 434];    // mfma output staging

    // ---- resident W fragments (load once; tn>=27 / k>=144 -> zero) ----
    bf16x8 wf[4][5];
    #pragma unroll
    for (int ti = 0; ti < 4; ++ti) {
        int tn = wave + 8 * ti;
        bool tvalid = (tn < 27);
        int tnc = tvalid ? tn : 0;
        const float* wr = &w_hh[(size_t)(tnc * 16 + ln) * 144];
        #pragma unroll
        for (int kt = 0; kt < 5; ++kt) {
            bool kval = tvalid && ((kt < 4) || (qd < 2));
            int kb = kt * 32 + qd * 8;
            float4 f0 = make_float4(0.f, 0.f, 0.f, 0.f);
            float4 f1 = make_float4(0.f, 0.f, 0.f, 0.f);
            if (kval) {
                f0 = *(const float4*)&wr[kb];
                f1 = *(const float4*)&wr[kb + 4];
            }
            bf16x8 v;
            v[0] = f2bf(f0.x); v[1] = f2bf(f0.y); v[2] = f2bf(f0.z); v[3] = f2bf(f0.w);
            v[4] = f2bf(f1.x); v[5] = f2bf(f1.y); v[6] = f2bf(f1.z); v[7] = f2bf(f1.w);
            wf[ti][kt] = v;
        }
    }

    // ---- gate-side state: thread (m, dbase) owns elems d = dbase+32*it ----
    int m = tid >> 5;                 // 0..15
    int dbase = tid & 31;
    int bglob = bb * 16 + m;

    float bhr[5], bhz[5], bhn[5], hold[5], hnreg[5];
    #pragma unroll
    for (int it = 0; it < 5; ++it) {
        int d = dbase + 32 * it;
        bool v = d < D_;
        bhr[it]   = v ? b_hh[d]        : 0.f;
        bhz[it]   = v ? b_hh[D_ + d]   : 0.f;
        bhn[it]   = v ? b_hh[2*D_ + d] : 0.f;
        hold[it]  = v ? h0[bglob * D_ + d] : 0.f;
        hnreg[it] = 0.f;
    }

    // ---- init h LDS (zero padding, then split-fill) ----
    for (int i = tid; i < 16 * 168; i += 512) { hH[i] = 0; hL[i] = 0; }
    __syncthreads();
    #pragma unroll
    for (int it = 0; it < 5; ++it) {
        int d = dbase + 32 * it;
        if (d < D_) {
            short hi = f2bf(hold[it]);
            hH[m * 168 + d] = hi;
            hL[m * 168 + d] = f2bf(hold[it] - bf2f(hi));
        }
    }
    __syncthreads();

    const float* gib = &gi[(size_t)bglob * T_ * G_];

    for (int step = 0; step < T_; ++step) {
        // deferred hseq store for step-1 (drains at barrier1, overlapped)
        if (step > 0) {
            float* hs = &hseq[((size_t)bglob * T_ + (step - 1)) * D_];
            #pragma unroll
            for (int it = 0; it < 5; ++it) {
                int d = dbase + 32 * it;
                if (d < D_) hs[d] = hnreg[it];
            }
        }
        // prefetch gi (consumed after barrier1; latency hides under MFMA)
        const float* gp = &gib[(size_t)step * G_];
        float gir[5], giz[5], gin[5];
        #pragma unroll
        for (int it = 0; it < 5; ++it) {
            int d = dbase + 32 * it;
            bool v = d < D_;
            gir[it] = v ? gp[d]        : 0.f;
            giz[it] = v ? gp[D_ + d]   : 0.f;
            gin[it] = v ? gp[2*D_ + d] : 0.f;
        }

        // A fragments (hi/lo) from LDS
        bf16x8 ah[5], al[5];
        #pragma unroll
        for (int kt = 0; kt < 5; ++kt) {
            ah[kt] = *(bf16x8*)&hH[ln * 168 + kt * 32 + qd * 8];
            al[kt] = *(bf16x8*)&hL[ln * 168 + kt * 32 + qd * 8];
        }

        // MFMA: acc[m][n] = sum_k (h_hi+h_lo)[m][k] * W[n][k]
        #pragma unroll
        for (int ti = 0; ti < 4; ++ti) {
            int tn = wave + 8 * ti;
            if (tn < 27) {
                f32x4 acc = {0.f, 0.f, 0.f, 0.f};
                #pragma unroll
                for (int kt = 0; kt < 5; ++kt) {
                    acc = __builtin_amdgcn_mfma_f32_16x16x32_bf16(ah[kt], wf[ti][kt], acc, 0, 0, 0);
                    acc = __builtin_amdgcn_mfma_f32_16x16x32_bf16(al[kt], wf[ti][kt], acc, 0, 0, 0);
                }
                int n = tn * 16 + ln;
                #pragma unroll
                for (int i = 0; i < 4; ++i)
                    gh[(qd * 4 + i) * 434 + n] = acc[i];
            }
        }
        __syncthreads();          // gh ready

        // fused gate (all 512 threads; h_old in registers)
        #pragma unroll
        for (int it = 0; it < 5; ++it) {
            int d = dbase + 32 * it;
            if (d < D_) {
                float ghr = gh[m * 434 + d];
                float ghz = gh[m * 434 + D_ + d];
                float ghn = gh[m * 434 + 2*D_ + d];
                float r = 1.f / (1.f + __expf(-(gir[it] + ghr + bhr[it])));
                float z = 1.f / (1.f + __expf(-(giz[it] + ghz + bhz[it])));
                float narg = gin[it] + r * (ghn + bhn[it]);
                narg = fminf(fmaxf(narg, -15.f), 15.f);
                float e2 = __expf(-2.f * narg);
                float nn = (1.f - e2) / (1.f + e2);
                float hn = (1.f - z) * nn + z * hold[it];
                hold[it] = hn;
                hnreg[it] = hn;
                short hi = f2bf(hn);
                hH[m * 168 + d] = hi;
                hL[m * 168 + d] = f2bf(hn - bf2f(hi));
            }
        }
        __syncthreads();          // h ready for next step
    }

    // final hseq row + hlast
    {
        float* hs = &hseq[((size_t)bglob * T_ + (T_ - 1)) * D_];
        #pragma unroll
        for (int it = 0; it < 5; ++it) {
            int d = dbase + 32 * it;
            if (d < D_) {
                hs[d] = hnreg[it];
                hlast[bglob * D_ + d] = hold[it];
            }
        }
    }
}

// ---------------------------------------------------------------------------
extern "C" void kernel_launch(void* const* d_in, const int* in_sizes, int n_in,
                              void* d_out, int out_size, void* d_ws, size_t ws_size,
                              hipStream_t stream)
{
    const int*   x         = (const int*)d_in[0];
    // d_in[1] = lengths (unused by the reference computation)
    const float* hidden    = (const float*)d_in[2];
    const float* encode_w  = (const float*)d_in[3];
    const float* wchange_w = (const float*)d_in[4];
    const float* w_ih      = (const float*)d_in[5];
    const float* w_hh      = (const float*)d_in[6];
    const float* b_ih      = (const float*)d_in[7];
    const float* b_hh      = (const float*)d_in[8];
    const float* fc_w      = (const float*)d_in[9];
    const float* fc_b      = (const float*)d_in[10];

    float* out = (float*)d_out;              // [N_][128] then [128][144]
    float* ws  = (float*)d_ws;
    float* seq  = ws;                        //   921600 floats
    float* gi   = ws + 921600;               //  2764800 floats
    float* hseq = ws + 921600 + 2764800;     //   921600 floats  (18.4 MB total)

    // K1: embedding (parallel gather v2)
    embed_kernel<<<N_, 256, 0, stream>>>(x, encode_w, wchange_w, seq);

    // K2: gi = seq @ w_ih^T + b_ih   (M=6400, N=432)
    gemm_bias_kernel<<<dim3(N_ / 64, (G_ + 63) / 64), 256, 0, stream>>>(
        seq, w_ih, b_ih, gi, N_, G_);

    // K3: GRU over T=50  (v8: MFMA, 8 blocks x 512, 16 batches/block)
    gru_kernel<<<8, 512, 0, stream>>>(gi, w_hh, b_hh, hidden, hseq,
                                      out + (size_t)N_ * E_);

    // K4: dynamic_user = hseq @ fc_w^T + fc_b   (M=6400, N=128)
    gemm_bias_kernel<<<dim3(N_ / 64, E_ / 64), 256, 0, stream>>>(
        hseq, fc_w, fc_b, out, N_, E_);
}

// Round 11
// 195.360 us; speedup vs baseline: 1.2923x; 1.2923x over previous
//
#include <hip/hip_runtime.h>
#include <math.h>

#define B_   128
#define T_   50
#define MI_  32
#define E_   128
#define EW_  16
#define D_   144
#define G_   432        // 3*D
#define N_   (B_*T_)    // 6400

// ---------------------------------------------------------------------------
// K1: basket embedding v2 — parallel gather (R7, kept).
// ---------------------------------------------------------------------------
__global__ __launch_bounds__(256) void embed_kernel(
    const int* __restrict__ x,            // [N_][33]
    const float* __restrict__ encode_w,   // [100000][128]  (row 0 == 0)
    const float* __restrict__ wchange_w,  // [2][16]
    float* __restrict__ seq)              // [N_][144]
{
    int n = blockIdx.x;
    int tid = threadIdx.x;
    int i = tid >> 3;        // item 0..31
    int j = tid & 7;         // col chunk [16j, 16j+16)

    __shared__ int xi[33];
    __shared__ __align__(16) float part[32 * 132];
    __shared__ float cntf[32];

    if (tid < 33) xi[tid] = x[n * 33 + tid];
    __syncthreads();

    int it = xi[i];
    const float* row = &encode_w[(size_t)it * E_];
    float4 v0 = *(const float4*)&row[16 * j + 0];
    float4 v1 = *(const float4*)&row[16 * j + 4];
    float4 v2 = *(const float4*)&row[16 * j + 8];
    float4 v3 = *(const float4*)&row[16 * j + 12];

    float* p = &part[i * 132 + 16 * j];
    *(float4*)&p[0]  = v0;
    *(float4*)&p[4]  = v1;
    *(float4*)&p[8]  = v2;
    *(float4*)&p[12] = v3;
    if (j == 0) cntf[i] = (it != 0) ? 1.f : 0.f;
    __syncthreads();

    if (tid < E_) {
        int c = tid;
        float s = 0.f, cn = 0.f;
        #pragma unroll
        for (int k = 0; k < 32; ++k) {
            s  += part[k * 132 + c];
            cn += cntf[k];
        }
        seq[n * D_ + c] = s / fmaxf(cn, 1.f);
    } else if (tid < E_ + EW_) {
        int c = tid - E_;
        seq[n * D_ + E_ + c] = wchange_w[xi[32] * EW_ + c];
    }
}

// ---------------------------------------------------------------------------
// K2/K4: C[M][N] = A[M][144] * Bw[N][144]^T + bias[N].  K fixed = 144.
// 64x64 tile, k-major LDS (pad 68 -> conflict-free b128 reads), BK=48.
// pack=1 (K2 only, N=432): write C[r][ (c%144)*3 + c/144 ] so the GRU's
// gate reads its 3 gi values ADJACENT (one cache line) instead of 144 apart.
// Same 432 row stride -> identical buffer size.
// ---------------------------------------------------------------------------
#define GK   144
#define GBK  48
#define GPAD 68

__global__ __launch_bounds__(256) void gemm_bias_kernel(
    const float* __restrict__ A,
    const float* __restrict__ Bw,
    const float* __restrict__ bias,
    float* __restrict__ C,
    int M, int N, int pack)
{
    __shared__ float As[GBK * GPAD];
    __shared__ float Bs[GBK * GPAD];

    int tid = threadIdx.x;
    int row0 = blockIdx.x * 64;
    int col0 = blockIdx.y * 64;
    int tx = tid & 15;
    int ty = tid >> 4;

    float acc[4][4] = {};

    int sr = tid >> 2;
    int skq0 = tid & 3;

    for (int k0 = 0; k0 < GK; k0 += GBK) {
        __syncthreads();
        #pragma unroll
        for (int i = 0; i < 3; ++i) {
            int kq = skq0 + i * 4;
            float4 a = *(const float4*)&A[(size_t)(row0 + sr) * GK + k0 + kq * 4];
            int nrow = col0 + sr;
            float4 b = make_float4(0.f, 0.f, 0.f, 0.f);
            if (nrow < N)
                b = *(const float4*)&Bw[(size_t)nrow * GK + k0 + kq * 4];
            As[(kq * 4 + 0) * GPAD + sr] = a.x;
            As[(kq * 4 + 1) * GPAD + sr] = a.y;
            As[(kq * 4 + 2) * GPAD + sr] = a.z;
            As[(kq * 4 + 3) * GPAD + sr] = a.w;
            Bs[(kq * 4 + 0) * GPAD + sr] = b.x;
            Bs[(kq * 4 + 1) * GPAD + sr] = b.y;
            Bs[(kq * 4 + 2) * GPAD + sr] = b.z;
            Bs[(kq * 4 + 3) * GPAD + sr] = b.w;
        }
        __syncthreads();

        #pragma unroll 4
        for (int k = 0; k < GBK; ++k) {
            float4 a4 = *(const float4*)&As[k * GPAD + ty * 4];
            float4 b4 = *(const float4*)&Bs[k * GPAD + tx * 4];
            float av[4] = {a4.x, a4.y, a4.z, a4.w};
            float bv[4] = {b4.x, b4.y, b4.z, b4.w};
            #pragma unroll
            for (int i = 0; i < 4; ++i)
                #pragma unroll
                for (int j = 0; j < 4; ++j)
                    acc[i][j] = fmaf(av[i], bv[j], acc[i][j]);
        }
    }

    int c = col0 + tx * 4;
    if (c < N) {
        float4 bb = *(const float4*)&bias[c];
        float bv[4] = {bb.x, bb.y, bb.z, bb.w};
        if (pack) {
            // column c+j -> slot (c+j)%144 * 3 + (c+j)/144
            int idx[4];
            #pragma unroll
            for (int j = 0; j < 4; ++j) {
                int cc = c + j;
                int gg = (cc >= 288) ? 2 : ((cc >= 144) ? 1 : 0);
                idx[j] = (cc - 144 * gg) * 3 + gg;
            }
            #pragma unroll
            for (int i = 0; i < 4; ++i) {
                int r = row0 + ty * 4 + i;
                #pragma unroll
                for (int j = 0; j < 4; ++j)
                    C[(size_t)r * N + idx[j]] = acc[i][j] + bv[j];
            }
        } else {
            #pragma unroll
            for (int i = 0; i < 4; ++i) {
                int r = row0 + ty * 4 + i;
                float4 o;
                o.x = acc[i][0] + bv[0];
                o.y = acc[i][1] + bv[1];
                o.z = acc[i][2] + bv[2];
                o.w = acc[i][3] + bv[3];
                *(float4*)&C[(size_t)r * N + c] = o;
            }
        }
    }
}

// ---------------------------------------------------------------------------
// K3: GRU v9 = v3 (proven 54.3us) + latency-pack:
//  (a) gh packed as gh4[d*4+g]: gate reads ONE ds_read_b128 instead of 3
//      scattered ds_read_b32 (removes ~2 LDS latency exposures per step);
//  (b) gi comes pre-transposed from K2 as [n][d*3+g]: the gate's 3 loads are
//      adjacent (one line) instead of 144 elements apart.
// Everything else identical to v3: 576 threads, g=tid>>3 owns rows 6g..6g+5,
// s=tid&7 owns k-chunk [20s,20s+20) (K zero-padded 160), w=6x20 VGPRs,
// 5 conflict-free ds_read_b128/step, 8-lane DPP butterfly reduction.
// ---------------------------------------------------------------------------
template<int CTRL>
__device__ __forceinline__ float dpp_xor_add(float x) {
    int y = __builtin_amdgcn_mov_dpp(__float_as_int(x), CTRL, 0xF, 0xF, true);
    return x + __int_as_float(y);
}

__global__ __launch_bounds__(576) void gru_kernel(
    const float* __restrict__ gi,     // [N_][432] packed [d*3+g]
    const float* __restrict__ w_hh,   // [432][144]
    const float* __restrict__ b_hh,   // [432]
    const float* __restrict__ h0,     // [128][144]
    float* __restrict__ hseq,         // [N_][144]
    float* __restrict__ hlast)        // [128][144]
{
    int b = blockIdx.x;
    int tid = threadIdx.x;
    int g = tid >> 3;       // 0..71  -> rows 6g..6g+5
    int s = tid & 7;        // k-chunk [20s, 20s+20)
    int k0 = s * 20;

    __shared__ __align__(16) float h[160];      // k-padded; [144..159] stay 0
    __shared__ __align__(16) float gh4[D_ * 4]; // [d][g] packed (w unused)

    // one-time: weights into VGPRs (zero-padded past k=143)
    float w[6][20];
    #pragma unroll
    for (int r = 0; r < 6; ++r) {
        const float* wrow = &w_hh[(size_t)(6 * g + r) * D_];
        #pragma unroll
        for (int q = 0; q < 5; ++q) {
            int k = k0 + 4 * q;
            float4 t = make_float4(0.f, 0.f, 0.f, 0.f);
            if (k < D_) t = *(const float4*)&wrow[k];   // k<=140, safe
            w[r][4 * q + 0] = t.x;
            w[r][4 * q + 1] = t.y;
            w[r][4 * q + 2] = t.z;
            w[r][4 * q + 3] = t.w;
        }
    }
    float bias = (s < 6) ? b_hh[6 * g + s] : 0.f;
    // packed gh slot for row 6g+s (s<6)
    int myrow = 6 * g + s;
    int mygg  = (myrow >= 288) ? 2 : ((myrow >= 144) ? 1 : 0);
    int myslot = (myrow - 144 * mygg) * 4 + mygg;

    if (tid < 160) h[tid] = (tid < D_) ? h0[b * D_ + tid] : 0.f;
    __syncthreads();

    for (int t = 0; t < T_; ++t) {
        int n = b * T_ + t;
        // prefetch gi (packed adjacent; L2-resident; hides under dot phase)
        float gir = 0.f, giz = 0.f, gin = 0.f;
        if (tid < D_) {
            const float* gp = &gi[(size_t)n * G_ + tid * 3];
            gir = gp[0];
            giz = gp[1];
            gin = gp[2];
        }

        // h chunk: 5 conflict-free ds_read_b128
        float hv[20];
        #pragma unroll
        for (int q = 0; q < 5; ++q) {
            float4 t4 = *(const float4*)&h[k0 + 4 * q];
            hv[4 * q + 0] = t4.x;
            hv[4 * q + 1] = t4.y;
            hv[4 * q + 2] = t4.z;
            hv[4 * q + 3] = t4.w;
        }

        // 6 rows x 20 k partial dots (120 fmac, 6 independent chains)
        float a0 = 0.f, a1 = 0.f, a2 = 0.f, a3 = 0.f, a4 = 0.f, a5 = 0.f;
        #pragma unroll
        for (int kk = 0; kk < 20; ++kk) {
            float hk = hv[kk];
            a0 = fmaf(w[0][kk], hk, a0);
            a1 = fmaf(w[1][kk], hk, a1);
            a2 = fmaf(w[2][kk], hk, a2);
            a3 = fmaf(w[3][kk], hk, a3);
            a4 = fmaf(w[4][kk], hk, a4);
            a5 = fmaf(w[5][kk], hk, a5);
        }

        // reduce across the 8 k-chunk lanes: VALU DPP butterfly (no LDS)
        a0 = dpp_xor_add<0xB1>(a0); a0 = dpp_xor_add<0x4E>(a0); a0 = dpp_xor_add<0x141>(a0);
        a1 = dpp_xor_add<0xB1>(a1); a1 = dpp_xor_add<0x4E>(a1); a1 = dpp_xor_add<0x141>(a1);
        a2 = dpp_xor_add<0xB1>(a2); a2 = dpp_xor_add<0x4E>(a2); a2 = dpp_xor_add<0x141>(a2);
        a3 = dpp_xor_add<0xB1>(a3); a3 = dpp_xor_add<0x4E>(a3); a3 = dpp_xor_add<0x141>(a3);
        a4 = dpp_xor_add<0xB1>(a4); a4 = dpp_xor_add<0x4E>(a4); a4 = dpp_xor_add<0x141>(a4);
        a5 = dpp_xor_add<0xB1>(a5); a5 = dpp_xor_add<0x4E>(a5); a5 = dpp_xor_add<0x141>(a5);

        // lane s writes its row's packed slot (s<6)
        float myacc = a0;
        if (s == 1) myacc = a1;
        if (s == 2) myacc = a2;
        if (s == 3) myacc = a3;
        if (s == 4) myacc = a4;
        if (s == 5) myacc = a5;
        if (s < 6) gh4[myslot] = myacc + bias;
        __syncthreads();

        if (tid < D_) {
            float4 q4 = *(const float4*)&gh4[tid * 4];   // r,z,n in one b128
            float r = 1.f / (1.f + __expf(-(gir + q4.x)));
            float z = 1.f / (1.f + __expf(-(giz + q4.y)));
            float narg = gin + r * q4.z;
            narg = fminf(fmaxf(narg, -15.f), 15.f);
            float e2 = __expf(-2.f * narg);
            float nn = (1.f - e2) / (1.f + e2);
            float hn = (1.f - z) * nn + z * h[tid];
            hseq[(size_t)n * D_ + tid] = hn;
            h[tid] = hn;
        }
        __syncthreads();
    }

    if (tid < D_) hlast[b * D_ + tid] = h[tid];
}

// ---------------------------------------------------------------------------
extern "C" void kernel_launch(void* const* d_in, const int* in_sizes, int n_in,
                              void* d_out, int out_size, void* d_ws, size_t ws_size,
                              hipStream_t stream)
{
    const int*   x         = (const int*)d_in[0];
    // d_in[1] = lengths (unused by the reference computation)
    const float* hidden    = (const float*)d_in[2];
    const float* encode_w  = (const float*)d_in[3];
    const float* wchange_w = (const float*)d_in[4];
    const float* w_ih      = (const float*)d_in[5];
    const float* w_hh      = (const float*)d_in[6];
    const float* b_ih      = (const float*)d_in[7];
    const float* b_hh      = (const float*)d_in[8];
    const float* fc_w      = (const float*)d_in[9];
    const float* fc_b      = (const float*)d_in[10];

    float* out = (float*)d_out;              // [N_][128] then [128][144]
    float* ws  = (float*)d_ws;
    float* seq  = ws;                        //   921600 floats
    float* gi   = ws + 921600;               //  2764800 floats (packed layout)
    float* hseq = ws + 921600 + 2764800;     //   921600 floats  (18.4 MB total)

    // K1: embedding (parallel gather v2)
    embed_kernel<<<N_, 256, 0, stream>>>(x, encode_w, wchange_w, seq);

    // K2: gi = seq @ w_ih^T + b_ih   (M=6400, N=432), packed [d*3+g] output
    gemm_bias_kernel<<<dim3(N_ / 64, (G_ + 63) / 64), 256, 0, stream>>>(
        seq, w_ih, b_ih, gi, N_, G_, 1);

    // K3: GRU over T=50  (v9 = v3 + gh4/gi latency-pack)
    gru_kernel<<<B_, 576, 0, stream>>>(gi, w_hh, b_hh, hidden, hseq,
                                       out + (size_t)N_ * E_);

    // K4: dynamic_user = hseq @ fc_w^T + fc_b   (M=6400, N=128)
    gemm_bias_kernel<<<dim3(N_ / 64, E_ / 64), 256, 0, stream>>>(
        hseq, fc_w, fc_b, out, N_, E_, 0);
}